// Round 8
// baseline (197.910 us; speedup 1.0000x reference)
//
#include <hip/hip_runtime.h>
#include <hip/hip_bf16.h>

// Problem constants
constexpr int N    = 2048;
constexpr int IN   = 256;
constexpr int OUT  = 512;
constexpr int NH   = 8;
constexpr int HD   = 64;      // OUT / NH
constexpr int NQK  = 1024;    // Q|K concatenated columns
constexpr int NC   = 16;      // key chunks for attention
constexpr int KPB  = N / NC;  // 128 keys per chunk
constexpr int KT   = KPB / 16;// 8 key-tiles of 16
constexpr int BLKS_PER_QG = NH * NC;  // 128 attn blocks per 256-query group

typedef _Float16  f16x8  __attribute__((ext_vector_type(8)));
typedef _Float16  f16x4  __attribute__((ext_vector_type(4)));
typedef float     f32x4  __attribute__((ext_vector_type(4)));

#if __has_builtin(__builtin_amdgcn_exp2f)
#define EXP2(x) __builtin_amdgcn_exp2f(x)
#else
#define EXP2(x) exp2f(x)
#endif

// Q is pre-scaled by 1/sqrt(64) * log2(e) so attention uses raw exp2.
#define QSCALE (0.125f * 1.44269504088896f)

// ---------------------------------------------------------------------------
// prep_wt_wvo: blocks 0..255  : WT[n'][k] = fp16 transpose of [Wq|Wk]
//              blocks 256..263: Wvo[i][h] = sum_d Wv[i][h*64+d]*Wo[h*64+d], bvo
//              blocks 264..271: zero pnum/pden accumulators (+ counters)
// ---------------------------------------------------------------------------
__global__ __launch_bounds__(256)
void prep_wt_wvo(const float* __restrict__ Wq, const float* __restrict__ Wk,
                 const float* __restrict__ Wv, const float* __restrict__ bv,
                 const float* __restrict__ Wo,
                 _Float16* __restrict__ WT,
                 float* __restrict__ Wvo, float* __restrict__ bvo,
                 float* __restrict__ pnum, int* __restrict__ cnt) {
    __shared__ float smem[32 * 33];   // transpose tile / wo_s
    const int b = blockIdx.x;
    const int tid = threadIdx.x;

    if (b < 256) {
        // ---- WT transpose via LDS 32x32 tile ----
        const int k0 = (b & 7) * 32;         // k tile
        const int n0 = (b >> 3) * 32;        // n' tile (never straddles 512)
        const float* W = (n0 < OUT) ? Wq : Wk;
        const int nc = (n0 < OUT) ? n0 : n0 - OUT;
        {
            const int row = tid >> 3;          // k within tile
            const int c4  = (tid & 7) * 4;     // n within tile
            const float4 v = *(const float4*)(W + (size_t)(k0 + row) * OUT + nc + c4);
            smem[row * 33 + c4 + 0] = v.x;
            smem[row * 33 + c4 + 1] = v.y;
            smem[row * 33 + c4 + 2] = v.z;
            smem[row * 33 + c4 + 3] = v.w;
        }
        __syncthreads();
        {
            const int nrow = tid >> 3;         // n within tile
            const int k4   = (tid & 7) * 4;    // k within tile
            f16x4 o;
            #pragma unroll
            for (int j = 0; j < 4; j++)
                o[j] = (_Float16)smem[(k4 + j) * 33 + nrow];
            *(f16x4*)(WT + (size_t)(n0 + nrow) * IN + k0 + k4) = o;
        }
    } else if (b < 264) {
        // ---- prep_wvo ----
        float* wo_s = smem;
        wo_s[tid]       = Wo[tid];
        wo_s[tid + 256] = Wo[tid + 256];
        __syncthreads();
        const int i = (b - 256) * 32 + (tid >> 3);
        const int h = tid & 7;
        const float* wr = Wv + (size_t)i * OUT + h * HD;
        float s = 0.f;
        #pragma unroll
        for (int d = 0; d < HD; d += 4) {
            const float4 v = *(const float4*)(wr + d);
            s += v.x * wo_s[h * HD + d + 0] + v.y * wo_s[h * HD + d + 1]
               + v.z * wo_s[h * HD + d + 2] + v.w * wo_s[h * HD + d + 3];
        }
        Wvo[i * NH + h] = s;
        if (b == 256 && tid < NH) {
            float sb = 0.f;
            #pragma unroll
            for (int d = 0; d < HD; d++)
                sb += bv[tid * HD + d] * wo_s[tid * HD + d];
            bvo[tid] = sb;
        }
    } else {
        // ---- zero pnum+pden (contiguous 2*NH*N floats) + counters ----
        float4* dst = (float4*)pnum + (size_t)(b - 264) * 1024 + tid;
        const float4 z = {0.f, 0.f, 0.f, 0.f};
        #pragma unroll
        for (int i = 0; i < 4; i++) dst[i * 256] = z;
        if (b == 264 && tid < NH) cnt[tid] = 0;
    }
}

// ---------------------------------------------------------------------------
// gemm_qk_vpm: blocks 0..511: fp16 MFMA GEMM C = x @ WT^T (A-frags built by
//   in-register fp32->fp16 cvt of x; B-frags from pre-transposed fp16 WT),
//   head-major fp16 output [h][m][d] (Q scaled by QSCALE, +bias).
// blocks 512..575: vpmT[h][k] = sigmoid(mg(k)) * (x[k] @ Wvo[:,h] + bvo[h])
// ---------------------------------------------------------------------------
__global__ __launch_bounds__(256)
void gemm_qk_vpm(const float* __restrict__ x, const _Float16* __restrict__ WT,
                 const float* __restrict__ bq, const float* __restrict__ bk,
                 _Float16* __restrict__ Qh, _Float16* __restrict__ Kh,
                 const float* __restrict__ rel_vel,
                 const float* __restrict__ rel_angle,
                 const float* __restrict__ Wmg1, const float* __restrict__ bmg1,
                 const float* __restrict__ Wmg2, const float* __restrict__ bmg2,
                 const float* __restrict__ Wvo, const float* __restrict__ bvo,
                 float* __restrict__ vpmT) {
    __shared__ _Float16 stage[32 * 132];  // gemm epilogue staging
    __shared__ float wvo_s[IN * NH];      // vpm weight cache (8 KB)
    const int tid = threadIdx.x;

    if (blockIdx.x >= 512) {
        // ================= vpm branch =================
        #pragma unroll
        for (int i = 0; i < 8; i++) wvo_s[tid + 256 * i] = Wvo[tid + 256 * i];
        __syncthreads();

        const int k = (blockIdx.x - 512) * 32 + (tid >> 3);
        const int h = tid & 7;

        const float m0 = rel_vel[k], m1 = rel_angle[k];
        float g = bmg2[0];
        #pragma unroll
        for (int j = 0; j < HD; j++) {
            float t = m0 * Wmg1[j] + m1 * Wmg1[HD + j] + bmg1[j];
            t = fmaxf(t, 0.f);
            g += t * Wmg2[j];
        }
        const float mg = 1.f / (1.f + __expf(-g));

        const float4* xr = (const float4*)(x + (size_t)k * IN);
        float a0 = 0.f, a1 = 0.f, a2 = 0.f, a3 = 0.f;
        #pragma unroll 4
        for (int i = 0; i < IN / 4; i++) {
            const float4 v = xr[i];
            a0 += v.x * wvo_s[(i * 4 + 0) * NH + h];
            a1 += v.y * wvo_s[(i * 4 + 1) * NH + h];
            a2 += v.z * wvo_s[(i * 4 + 2) * NH + h];
            a3 += v.w * wvo_s[(i * 4 + 3) * NH + h];
        }
        vpmT[h * N + k] = mg * (a0 + a1 + a2 + a3 + bvo[h]);
        return;
    }

    // ================= gemm branch =================
    const int lane = tid & 63;
    const int wave = tid >> 6;
    const int row16 = lane & 15;
    const int quad  = lane >> 4;
    const int nb0 = (blockIdx.x & 7) * 128;
    const int mb  = (blockIdx.x >> 3) * 32;
    const int nb  = nb0 + wave * 32;

    const size_t ar[2] = {(size_t)(mb + row16) * IN, (size_t)(mb + 16 + row16) * IN};
    const size_t br[2] = {(size_t)(nb + row16) * IN, (size_t)(nb + 16 + row16) * IN};

    f32x4 acc[2][2] = {};
    for (int k0 = 0; k0 < IN; k0 += 32) {
        const int ko = k0 + quad * 8;
        f16x8 a[2], bf[2];
        #pragma unroll
        for (int t = 0; t < 2; t++) {
            const float4 u0 = *(const float4*)(x + ar[t] + ko);
            const float4 u1 = *(const float4*)(x + ar[t] + ko + 4);
            f16x8 av;
            av[0] = (_Float16)u0.x; av[1] = (_Float16)u0.y;
            av[2] = (_Float16)u0.z; av[3] = (_Float16)u0.w;
            av[4] = (_Float16)u1.x; av[5] = (_Float16)u1.y;
            av[6] = (_Float16)u1.z; av[7] = (_Float16)u1.w;
            a[t]  = av;
            bf[t] = *(const f16x8*)(WT + br[t] + ko);
        }
        #pragma unroll
        for (int mt = 0; mt < 2; mt++)
            #pragma unroll
            for (int nt = 0; nt < 2; nt++)
                acc[mt][nt] = __builtin_amdgcn_mfma_f32_16x16x32_f16(a[mt], bf[nt], acc[mt][nt], 0, 0, 0);
    }

    // stage into LDS (C layout: col n = lane&15, row m = quad*4+r)
    const bool isQ = (nb0 < OUT);   // block-uniform
    const float scale = isQ ? QSCALE : 1.0f;
    #pragma unroll
    for (int mt = 0; mt < 2; mt++)
        #pragma unroll
        for (int nt = 0; nt < 2; nt++) {
            const int nl = wave * 32 + nt * 16 + row16;   // 0..127
            const int np = nb0 + nl;
            const int nq = isQ ? np : np - OUT;
            const float bias = isQ ? bq[nq] : bk[nq];
            #pragma unroll
            for (int r = 0; r < 4; r++) {
                const int ml = mt * 16 + quad * 4 + r;    // 0..31
                stage[ml * 132 + nl] = (_Float16)((acc[mt][nt][r] + bias) * scale);
            }
        }
    __syncthreads();

    // write out full lines: 64 rows (2 heads x 32 m) x 128B each
    _Float16* dst = isQ ? Qh : Kh;
    const int r2   = tid >> 2;         // 0..63
    const int cidx = tid & 3;          // 32B chunk
    const int hl   = r2 >> 5;          // head within block
    const int m    = r2 & 31;
    const int nqh  = (isQ ? nb0 : nb0 - OUT) + hl * 64;
    const int h    = nqh >> 6;
    const size_t goff = ((size_t)h * N + mb + m) * HD + cidx * 16;
    const int soff = m * 132 + hl * 64 + cidx * 16;
    *(f16x8*)(dst + goff)     = *(const f16x8*)(&stage[soff]);
    *(f16x8*)(dst + goff + 8) = *(const f16x8*)(&stage[soff + 8]);
}

// ---------------------------------------------------------------------------
// Attention + fused finalize.  fp16 MFMA, A=K (streamed) / B=Q (resident).
// Grid 1024: h = b&7 (XCD pin), c (16) x qg (8).  Partials accumulate into
// pnum/pden[h][q] via device-scope atomicAdd; the last block of each 256-q
// group (counted via cnt[qg]) computes out[q] = bo + sum_h num/den.
// ---------------------------------------------------------------------------
__global__ __launch_bounds__(256)
void attn_final(const _Float16* __restrict__ Qh, const _Float16* __restrict__ Kh,
                const float* __restrict__ vpmT,
                float* __restrict__ pnum, float* __restrict__ pden,
                int* __restrict__ cnt, const float* __restrict__ bo,
                float* __restrict__ out) {
    __shared__ int last_flag;
    const int b = blockIdx.x;
    const int h = b & 7;
    const int r = b >> 3;             // 0..127
    const int c = r >> 3;             // key chunk 0..15
    const int qg = r & 7;             // q-group 0..7
    const int lane = threadIdx.x & 63;
    const int wave = threadIdx.x >> 6;
    const int q0 = (qg * 4 + wave) * 64;
    const int row16 = lane & 15;
    const int quad  = lane >> 4;

    // B fragments (Q): B[n=lane&15][k=quad*8+j]; 4 q-tiles x 2 d-halves
    f16x8 Bq[4][2];
    #pragma unroll
    for (int qt = 0; qt < 4; qt++) {
        const size_t qoff = ((size_t)h * N + q0 + qt * 16 + row16) * HD + quad * 8;
        Bq[qt][0] = *(const f16x8*)(Qh + qoff);
        Bq[qt][1] = *(const f16x8*)(Qh + qoff + 32);
    }

    float num[4] = {}, den[4] = {};
    const int k0 = c * KPB;
    const size_t kbase = ((size_t)h * N + k0 + row16) * HD + quad * 8;
    const float* vp = vpmT + h * N + k0 + quad * 4;

    // register double-buffer the K tile + vpm
    f16x8 A0 = *(const f16x8*)(Kh + kbase);
    f16x8 A1 = *(const f16x8*)(Kh + kbase + 32);
    f32x4 vv = *(const f32x4*)(vp);

    #pragma unroll
    for (int t = 0; t < KT; t++) {
        const int tn = (t + 1 < KT) ? t + 1 : t;
        const size_t ka = kbase + (size_t)tn * 16 * HD;
        const f16x8 nA0 = *(const f16x8*)(Kh + ka);
        const f16x8 nA1 = *(const f16x8*)(Kh + ka + 32);
        const f32x4 nvv = *(const f32x4*)(vp + tn * 16);

        #pragma unroll
        for (int qt = 0; qt < 4; qt++) {
            f32x4 s = {0.f, 0.f, 0.f, 0.f};
            s = __builtin_amdgcn_mfma_f32_16x16x32_f16(A0, Bq[qt][0], s, 0, 0, 0);
            s = __builtin_amdgcn_mfma_f32_16x16x32_f16(A1, Bq[qt][1], s, 0, 0, 0);
            #pragma unroll
            for (int r4 = 0; r4 < 4; r4++) {
                const float e = EXP2(s[r4]);          // key = k0+t*16+quad*4+r4
                num[qt] += e * vv[r4];
                den[qt] += e;
            }
        }
        A0 = nA0; A1 = nA1; vv = nvv;
    }

    // reduce over quads (keys live on the quad dimension), accumulate global
    #pragma unroll
    for (int qt = 0; qt < 4; qt++) {
        float n = num[qt], d = den[qt];
        n += __shfl_xor(n, 16, 64);  d += __shfl_xor(d, 16, 64);
        n += __shfl_xor(n, 32, 64);  d += __shfl_xor(d, 32, 64);
        if (quad == 0) {
            const int q = q0 + qt * 16 + row16;
            atomicAdd(&pnum[(size_t)h * N + q], n);
            atomicAdd(&pden[(size_t)h * N + q], d);
        }
    }

    // last block of this 256-query group finalizes
    __threadfence();
    if (threadIdx.x == 0) {
        const int old = __hip_atomic_fetch_add(&cnt[qg], 1, __ATOMIC_ACQ_REL,
                                               __HIP_MEMORY_SCOPE_AGENT);
        last_flag = (old == BLKS_PER_QG - 1);
    }
    __syncthreads();
    if (last_flag) {
        const int q = qg * 256 + threadIdx.x;
        float acc = bo[0];
        #pragma unroll
        for (int hh = 0; hh < NH; hh++) {
            const float n = __hip_atomic_load(&pnum[(size_t)hh * N + q],
                                              __ATOMIC_RELAXED, __HIP_MEMORY_SCOPE_AGENT);
            const float d = __hip_atomic_load(&pden[(size_t)hh * N + q],
                                              __ATOMIC_RELAXED, __HIP_MEMORY_SCOPE_AGENT);
            acc += n / d;
        }
        out[q] = acc;
    }
}

// ---------------------------------------------------------------------------
extern "C" void kernel_launch(void* const* d_in, const int* in_sizes, int n_in,
                              void* d_out, int out_size, void* d_ws, size_t ws_size,
                              hipStream_t stream) {
    const float* x         = (const float*)d_in[0];
    // d_in[1] = rel_pos (unused: per-query bias cancels in softmax)
    const float* rel_vel   = (const float*)d_in[2];
    const float* rel_angle = (const float*)d_in[3];
    const float* Wq        = (const float*)d_in[4];
    const float* bq        = (const float*)d_in[5];
    const float* Wk        = (const float*)d_in[6];
    const float* bk        = (const float*)d_in[7];
    const float* Wv        = (const float*)d_in[8];
    const float* bv        = (const float*)d_in[9];
    // d_in[10..13] = Wsb1,bsb1,Wsb2,bsb2 (unused)
    const float* Wmg1      = (const float*)d_in[14];
    const float* bmg1      = (const float*)d_in[15];
    const float* Wmg2      = (const float*)d_in[16];
    const float* bmg2      = (const float*)d_in[17];
    const float* Wo        = (const float*)d_in[18];
    const float* bo        = (const float*)d_in[19];
    float* out = (float*)d_out;

    // workspace layout
    _Float16* WT  = (_Float16*)d_ws;                      // NQK*IN
    _Float16* Qh  = WT + (size_t)NQK * IN;                // [NH][N][HD]
    _Float16* Kh  = Qh + (size_t)NH * N * HD;
    float* fp     = (float*)(Kh + (size_t)NH * N * HD);
    float* Wvo    = fp;                          // IN*NH
    float* bvo    = Wvo + IN * NH;               // NH
    float* vpmT   = bvo + NH;                    // NH*N
    float* pnum   = vpmT + NH * N;               // NH*N  (accumulators)
    float* pden   = pnum + (size_t)NH * N;       // NH*N  (contiguous after pnum)
    int*   cnt    = (int*)(pden + (size_t)NH * N);  // NH counters (use 8)

    hipLaunchKernelGGL(prep_wt_wvo, dim3(272), dim3(256), 0, stream,
                       Wq, Wk, Wv, bv, Wo, WT, Wvo, bvo, pnum, cnt);
    hipLaunchKernelGGL(gemm_qk_vpm, dim3(576), dim3(256), 0, stream,
                       x, WT, bq, bk, Qh, Kh,
                       rel_vel, rel_angle, Wmg1, bmg1, Wmg2, bmg2, Wvo, bvo, vpmT);
    hipLaunchKernelGGL(attn_final, dim3(1024), dim3(256), 0, stream,
                       Qh, Kh, vpmT, pnum, pden, cnt, bo, out);
}

// Round 9
// 133.047 us; speedup vs baseline: 1.4875x; 1.4875x over previous
//
#include <hip/hip_runtime.h>
#include <hip/hip_bf16.h>

// Problem constants
constexpr int N    = 2048;
constexpr int IN   = 256;
constexpr int OUT  = 512;
constexpr int NH   = 8;
constexpr int HD   = 64;      // OUT / NH
constexpr int NQK  = 1024;    // Q|K concatenated columns
constexpr int NC   = 16;      // key chunks for attention
constexpr int KPB  = N / NC;  // 128 keys per chunk
constexpr int KT   = KPB / 16;// 8 key-tiles of 16

typedef _Float16  f16x8  __attribute__((ext_vector_type(8)));
typedef _Float16  f16x4  __attribute__((ext_vector_type(4)));
typedef float     f32x4  __attribute__((ext_vector_type(4)));

#if __has_builtin(__builtin_amdgcn_exp2f)
#define EXP2(x) __builtin_amdgcn_exp2f(x)
#else
#define EXP2(x) exp2f(x)
#endif

// Q is pre-scaled by 1/sqrt(64) * log2(e) so attention uses raw exp2.
#define QSCALE (0.125f * 1.44269504088896f)

// ---------------------------------------------------------------------------
// prep_all: blocks 0..511  : x -> fp16 X16 (same layout)
//           blocks 512..767: WT[n'][k] = fp16 transpose of [Wq|Wk]
//           blocks 768..775: Wvo[i][h] = sum_d Wv[i][h*64+d]*Wo[h*64+d], bvo
// ---------------------------------------------------------------------------
__global__ __launch_bounds__(256)
void prep_all(const float* __restrict__ x,
              const float* __restrict__ Wq, const float* __restrict__ Wk,
              const float* __restrict__ Wv, const float* __restrict__ bv,
              const float* __restrict__ Wo,
              _Float16* __restrict__ X16, _Float16* __restrict__ WT,
              float* __restrict__ Wvo, float* __restrict__ bvo) {
    __shared__ float smem[32 * 33];   // transpose tile / wo_s
    const int b = blockIdx.x;
    const int tid = threadIdx.x;

    if (b < 512) {
        // ---- x -> fp16 ----
        const size_t i4 = ((size_t)b * 256 + tid) * 4;
        const float4 v = *(const float4*)(x + i4);
        f16x4 o;
        o[0] = (_Float16)v.x; o[1] = (_Float16)v.y;
        o[2] = (_Float16)v.z; o[3] = (_Float16)v.w;
        *(f16x4*)(X16 + i4) = o;
    } else if (b < 768) {
        // ---- WT transpose via LDS 32x32 tile ----
        const int tb = b - 512;
        const int k0 = (tb & 7) * 32;        // k tile
        const int n0 = (tb >> 3) * 32;       // n' tile (never straddles 512)
        const float* W = (n0 < OUT) ? Wq : Wk;
        const int nc = (n0 < OUT) ? n0 : n0 - OUT;
        {
            const int row = tid >> 3;          // k within tile
            const int c4  = (tid & 7) * 4;     // n within tile
            const float4 v = *(const float4*)(W + (size_t)(k0 + row) * OUT + nc + c4);
            smem[row * 33 + c4 + 0] = v.x;
            smem[row * 33 + c4 + 1] = v.y;
            smem[row * 33 + c4 + 2] = v.z;
            smem[row * 33 + c4 + 3] = v.w;
        }
        __syncthreads();
        {
            const int nrow = tid >> 3;         // n within tile
            const int k4   = (tid & 7) * 4;    // k within tile
            f16x4 o;
            #pragma unroll
            for (int j = 0; j < 4; j++)
                o[j] = (_Float16)smem[(k4 + j) * 33 + nrow];
            *(f16x4*)(WT + (size_t)(n0 + nrow) * IN + k0 + k4) = o;
        }
    } else {
        // ---- prep_wvo ----
        float* wo_s = smem;
        wo_s[tid]       = Wo[tid];
        wo_s[tid + 256] = Wo[tid + 256];
        __syncthreads();
        const int i = (b - 768) * 32 + (tid >> 3);
        const int h = tid & 7;
        const float* wr = Wv + (size_t)i * OUT + h * HD;
        float s = 0.f;
        #pragma unroll
        for (int d = 0; d < HD; d += 4) {
            const float4 v = *(const float4*)(wr + d);
            s += v.x * wo_s[h * HD + d + 0] + v.y * wo_s[h * HD + d + 1]
               + v.z * wo_s[h * HD + d + 2] + v.w * wo_s[h * HD + d + 3];
        }
        Wvo[i * NH + h] = s;
        if (b == 768 && tid < NH) {
            float sb = 0.f;
            #pragma unroll
            for (int d = 0; d < HD; d++)
                sb += bv[tid * HD + d] * wo_s[tid * HD + d];
            bvo[tid] = sb;
        }
    }
}

// ---------------------------------------------------------------------------
// gemm_qk_vpm: blocks 0..511: fp16 MFMA GEMM C = X16 @ WT^T, head-major
//   fp16 output [h][m][d] (Q scaled by QSCALE, +bias).
// blocks 512..575: vpmT[h][k] = sigmoid(mg(k)) * (x[k] @ Wvo[:,h] + bvo[h])
// ---------------------------------------------------------------------------
__global__ __launch_bounds__(256)
void gemm_qk_vpm(const _Float16* __restrict__ X16, const _Float16* __restrict__ WT,
                 const float* __restrict__ bq, const float* __restrict__ bk,
                 _Float16* __restrict__ Qh, _Float16* __restrict__ Kh,
                 const float* __restrict__ x, const float* __restrict__ rel_vel,
                 const float* __restrict__ rel_angle,
                 const float* __restrict__ Wmg1, const float* __restrict__ bmg1,
                 const float* __restrict__ Wmg2, const float* __restrict__ bmg2,
                 const float* __restrict__ Wvo, const float* __restrict__ bvo,
                 float* __restrict__ vpmT) {
    __shared__ _Float16 stage[32 * 132];  // gemm epilogue staging
    __shared__ float wvo_s[IN * NH];      // vpm weight cache (8 KB)
    const int tid = threadIdx.x;

    if (blockIdx.x >= 512) {
        // ================= vpm branch =================
        #pragma unroll
        for (int i = 0; i < 8; i++) wvo_s[tid + 256 * i] = Wvo[tid + 256 * i];
        __syncthreads();

        const int k = (blockIdx.x - 512) * 32 + (tid >> 3);
        const int h = tid & 7;

        const float m0 = rel_vel[k], m1 = rel_angle[k];
        float g = bmg2[0];
        #pragma unroll
        for (int j = 0; j < HD; j++) {
            float t = m0 * Wmg1[j] + m1 * Wmg1[HD + j] + bmg1[j];
            t = fmaxf(t, 0.f);
            g += t * Wmg2[j];
        }
        const float mg = 1.f / (1.f + __expf(-g));

        const float4* xr = (const float4*)(x + (size_t)k * IN);
        float a0 = 0.f, a1 = 0.f, a2 = 0.f, a3 = 0.f;
        #pragma unroll 4
        for (int i = 0; i < IN / 4; i++) {
            const float4 v = xr[i];
            a0 += v.x * wvo_s[(i * 4 + 0) * NH + h];
            a1 += v.y * wvo_s[(i * 4 + 1) * NH + h];
            a2 += v.z * wvo_s[(i * 4 + 2) * NH + h];
            a3 += v.w * wvo_s[(i * 4 + 3) * NH + h];
        }
        vpmT[h * N + k] = mg * (a0 + a1 + a2 + a3 + bvo[h]);
        return;
    }

    // ================= gemm branch =================
    const int lane = tid & 63;
    const int wave = tid >> 6;
    const int row16 = lane & 15;
    const int quad  = lane >> 4;
    const int nb0 = (blockIdx.x & 7) * 128;
    const int mb  = (blockIdx.x >> 3) * 32;
    const int nb  = nb0 + wave * 32;

    const size_t ar[2] = {(size_t)(mb + row16) * IN, (size_t)(mb + 16 + row16) * IN};
    const size_t br[2] = {(size_t)(nb + row16) * IN, (size_t)(nb + 16 + row16) * IN};

    f32x4 acc[2][2] = {};
    for (int k0 = 0; k0 < IN; k0 += 32) {
        const int ko = k0 + quad * 8;
        f16x8 a[2], bf[2];
        #pragma unroll
        for (int t = 0; t < 2; t++) {
            a[t]  = *(const f16x8*)(X16 + ar[t] + ko);
            bf[t] = *(const f16x8*)(WT + br[t] + ko);
        }
        #pragma unroll
        for (int mt = 0; mt < 2; mt++)
            #pragma unroll
            for (int nt = 0; nt < 2; nt++)
                acc[mt][nt] = __builtin_amdgcn_mfma_f32_16x16x32_f16(a[mt], bf[nt], acc[mt][nt], 0, 0, 0);
    }

    // stage into LDS (C layout: col n = lane&15, row m = quad*4+r)
    const bool isQ = (nb0 < OUT);   // block-uniform
    const float scale = isQ ? QSCALE : 1.0f;
    #pragma unroll
    for (int mt = 0; mt < 2; mt++)
        #pragma unroll
        for (int nt = 0; nt < 2; nt++) {
            const int nl = wave * 32 + nt * 16 + row16;   // 0..127
            const int np = nb0 + nl;
            const int nq = isQ ? np : np - OUT;
            const float bias = isQ ? bq[nq] : bk[nq];
            #pragma unroll
            for (int r = 0; r < 4; r++) {
                const int ml = mt * 16 + quad * 4 + r;    // 0..31
                stage[ml * 132 + nl] = (_Float16)((acc[mt][nt][r] + bias) * scale);
            }
        }
    __syncthreads();

    // write out full lines: 64 rows (2 heads x 32 m) x 128B each
    _Float16* dst = isQ ? Qh : Kh;
    const int r2   = tid >> 2;         // 0..63
    const int cidx = tid & 3;          // 32B chunk
    const int hl   = r2 >> 5;          // head within block
    const int m    = r2 & 31;
    const int nqh  = (isQ ? nb0 : nb0 - OUT) + hl * 64;
    const int h    = nqh >> 6;
    const size_t goff = ((size_t)h * N + mb + m) * HD + cidx * 16;
    const int soff = m * 132 + hl * 64 + cidx * 16;
    *(f16x8*)(dst + goff)     = *(const f16x8*)(&stage[soff]);
    *(f16x8*)(dst + goff + 8) = *(const f16x8*)(&stage[soff + 8]);
}

// ---------------------------------------------------------------------------
// Attention partials, fp16 MFMA, A=K (streamed) / B=Q (64 q resident).
// Wave = 64 q x 128 k for one head; block = 4 waves; grid 1024:
// h = b&7 (XCD pin), then c (16) x qg (8).  4 blocks/CU -> 4 waves/SIMD.
// ---------------------------------------------------------------------------
__global__ __launch_bounds__(256)
void attn_mfma(const _Float16* __restrict__ Qh, const _Float16* __restrict__ Kh,
               const float* __restrict__ vpmT,
               float* __restrict__ pnum, float* __restrict__ pden) {
    const int b = blockIdx.x;
    const int h = b & 7;
    const int r = b >> 3;             // 0..127
    const int c = r >> 3;             // key chunk 0..15
    const int qg = r & 7;             // q-group 0..7
    const int lane = threadIdx.x & 63;
    const int wave = threadIdx.x >> 6;
    const int q0 = (qg * 4 + wave) * 64;
    const int row16 = lane & 15;
    const int quad  = lane >> 4;

    // B fragments (Q): B[n=lane&15][k=quad*8+j]; 4 q-tiles x 2 d-halves
    f16x8 Bq[4][2];
    #pragma unroll
    for (int qt = 0; qt < 4; qt++) {
        const size_t qoff = ((size_t)h * N + q0 + qt * 16 + row16) * HD + quad * 8;
        Bq[qt][0] = *(const f16x8*)(Qh + qoff);
        Bq[qt][1] = *(const f16x8*)(Qh + qoff + 32);
    }

    float num[4] = {}, den[4] = {};
    const int k0 = c * KPB;
    const size_t kbase = ((size_t)h * N + k0 + row16) * HD + quad * 8;
    const float* vp = vpmT + h * N + k0 + quad * 4;

    // register double-buffer the K tile + vpm
    f16x8 A0 = *(const f16x8*)(Kh + kbase);
    f16x8 A1 = *(const f16x8*)(Kh + kbase + 32);
    f32x4 vv = *(const f32x4*)(vp);

    #pragma unroll
    for (int t = 0; t < KT; t++) {
        const int tn = (t + 1 < KT) ? t + 1 : t;
        const size_t ka = kbase + (size_t)tn * 16 * HD;
        const f16x8 nA0 = *(const f16x8*)(Kh + ka);
        const f16x8 nA1 = *(const f16x8*)(Kh + ka + 32);
        const f32x4 nvv = *(const f32x4*)(vp + tn * 16);

        #pragma unroll
        for (int qt = 0; qt < 4; qt++) {
            f32x4 s = {0.f, 0.f, 0.f, 0.f};
            s = __builtin_amdgcn_mfma_f32_16x16x32_f16(A0, Bq[qt][0], s, 0, 0, 0);
            s = __builtin_amdgcn_mfma_f32_16x16x32_f16(A1, Bq[qt][1], s, 0, 0, 0);
            #pragma unroll
            for (int r4 = 0; r4 < 4; r4++) {
                const float e = EXP2(s[r4]);          // key = k0+t*16+quad*4+r4
                num[qt] += e * vv[r4];
                den[qt] += e;
            }
        }
        A0 = nA0; A1 = nA1; vv = nvv;
    }

    // reduce over quads (keys live on the quad dimension)
    #pragma unroll
    for (int qt = 0; qt < 4; qt++) {
        float n = num[qt], d = den[qt];
        n += __shfl_xor(n, 16, 64);  d += __shfl_xor(d, 16, 64);
        n += __shfl_xor(n, 32, 64);  d += __shfl_xor(d, 32, 64);
        if (quad == 0) {
            const int q = q0 + qt * 16 + row16;
            pnum[((size_t)c * NH + h) * N + q] = n;
            pden[((size_t)c * NH + h) * N + q] = d;
        }
    }
}

// ---------------------------------------------------------------------------
// finalize: out[q] = bo + sum_h (sum_c num) / (sum_c den)
// grid 8 x 256 (one thread per q); partial reads are coalesced across threads.
// ---------------------------------------------------------------------------
__global__ __launch_bounds__(256)
void finalize(const float* __restrict__ pnum, const float* __restrict__ pden,
              const float* __restrict__ bo, float* __restrict__ out) {
    const int q = blockIdx.x * 256 + threadIdx.x;
    float acc = bo[0];
    #pragma unroll
    for (int h = 0; h < NH; h++) {
        float num = 0.f, den = 0.f;
        #pragma unroll
        for (int ci = 0; ci < NC; ci++) {
            num += pnum[((size_t)ci * NH + h) * N + q];
            den += pden[((size_t)ci * NH + h) * N + q];
        }
        acc += num / den;
    }
    out[q] = acc;
}

// ---------------------------------------------------------------------------
extern "C" void kernel_launch(void* const* d_in, const int* in_sizes, int n_in,
                              void* d_out, int out_size, void* d_ws, size_t ws_size,
                              hipStream_t stream) {
    const float* x         = (const float*)d_in[0];
    // d_in[1] = rel_pos (unused: per-query bias cancels in softmax)
    const float* rel_vel   = (const float*)d_in[2];
    const float* rel_angle = (const float*)d_in[3];
    const float* Wq        = (const float*)d_in[4];
    const float* bq        = (const float*)d_in[5];
    const float* Wk        = (const float*)d_in[6];
    const float* bk        = (const float*)d_in[7];
    const float* Wv        = (const float*)d_in[8];
    const float* bv        = (const float*)d_in[9];
    // d_in[10..13] = Wsb1,bsb1,Wsb2,bsb2 (unused)
    const float* Wmg1      = (const float*)d_in[14];
    const float* bmg1      = (const float*)d_in[15];
    const float* Wmg2      = (const float*)d_in[16];
    const float* bmg2      = (const float*)d_in[17];
    const float* Wo        = (const float*)d_in[18];
    const float* bo        = (const float*)d_in[19];
    float* out = (float*)d_out;

    // workspace layout
    _Float16* X16 = (_Float16*)d_ws;                      // N*IN
    _Float16* WT  = X16 + (size_t)N * IN;                 // NQK*IN
    _Float16* Qh  = WT + (size_t)NQK * IN;                // [NH][N][HD]
    _Float16* Kh  = Qh + (size_t)NH * N * HD;
    float* fp     = (float*)(Kh + (size_t)NH * N * HD);
    float* Wvo    = fp;                          // IN*NH
    float* bvo    = Wvo + IN * NH;               // NH
    float* vpmT   = bvo + NH;                    // NH*N
    float* pnum   = vpmT + NH * N;               // NC*NH*N
    float* pden   = pnum + (size_t)NC * NH * N;  // NC*NH*N

    hipLaunchKernelGGL(prep_all, dim3(776), dim3(256), 0, stream,
                       x, Wq, Wk, Wv, bv, Wo, X16, WT, Wvo, bvo);
    hipLaunchKernelGGL(gemm_qk_vpm, dim3(576), dim3(256), 0, stream,
                       X16, WT, bq, bk, Qh, Kh,
                       x, rel_vel, rel_angle, Wmg1, bmg1, Wmg2, bmg2, Wvo, bvo, vpmT);
    hipLaunchKernelGGL(attn_mfma, dim3(1024), dim3(256), 0, stream,
                       Qh, Kh, vpmT, pnum, pden);
    hipLaunchKernelGGL(finalize, dim3(8), dim3(256), 0, stream, pnum, pden, bo, out);
}